// Round 5
// baseline (263.354 us; speedup 1.0000x reference)
//
#include <hip/hip_runtime.h>
#include <hip/hip_bf16.h>

// Problem constants
#define Bc   2
#define Nc   4096
#define Hc   4
#define HIDc 256
#define VDc  64

typedef short s8v  __attribute__((ext_vector_type(8)));
typedef float f4v  __attribute__((ext_vector_type(4)));

static __device__ __forceinline__ unsigned short bf16bits(float f) {
    __hip_bfloat16 h = __float2bfloat16(f);
    return *(unsigned short*)&h;
}

// ---------------------------------------------------------------------------
// K1 (fused): blocks 0..127 = W-prep (bf16 hi/lo split into MFMA-A-fragment-
// linear layout); blocks 128..8319 = per-row exact 30th percentile + row min.
// Thresh: windowed histogram on [0.25,0.35] (ranks 1228/1229 of U[0,1) rows
// land there with ~7 sigma margin); exact full-range fallback if not.
// ---------------------------------------------------------------------------
__global__ __launch_bounds__(256) void front_kernel(
    const float* __restrict__ m_dist, const float* __restrict__ wgt,
    unsigned short* __restrict__ wh, unsigned short* __restrict__ wl,
    float* __restrict__ thr_out, float* __restrict__ min_out)
{
    int t = threadIdx.x, bid = blockIdx.x;

    if (bid < 128) {
        int h  = bid >> 5;
        int kt = (bid >> 3) & 3;
        int jc = bid & 7;
        int lane = t >> 2, ii = t & 3;
        #pragma unroll
        for (int u = 0; u < 2; u++) {
            int i = ii * 2 + u;
            int j = jc * 32 + (lane >> 4) * 8 + i;
            int k = kt * 16 + (lane & 15);
            float v = wgt[((size_t)h * HIDc + j) * VDc + k];
            __hip_bfloat16 hb = __float2bfloat16(v);
            float hf = __bfloat162float(hb);
            size_t o = ((((size_t)h * 4 + kt) * 8 + jc) * 64 + lane) * 8 + i;
            wh[o] = *(unsigned short*)&hb;
            wl[o] = bf16bits(v - hf);
        }
        return;
    }

    __shared__ unsigned int hist[1024];
    __shared__ float wredf[4];
    __shared__ unsigned int wsum[4];
    __shared__ unsigned int wscan[4];
    __shared__ int b0s, b1s;
    __shared__ unsigned int c0s;
    __shared__ unsigned int ncand;
    __shared__ float cand[256];
    __shared__ float s0s, s1s;

    size_t rowid = bid - 128;
    const float* row = m_dist + rowid * Nc;

    float4 vals[4];
    float lmin = 1e30f;
    #pragma unroll
    for (int i = 0; i < 4; i++) {
        float4 v = ((const float4*)row)[t + i * 256];
        vals[i] = v;
        lmin = fminf(lmin, fminf(fminf(v.x, v.y), fminf(v.z, v.w)));
    }
    #pragma unroll
    for (int o = 32; o > 0; o >>= 1) lmin = fminf(lmin, __shfl_xor(lmin, o));
    if ((t & 63) == 0) wredf[t >> 6] = lmin;

    const unsigned int R0 = 1228u, R1 = 1229u;
    float wlo = 0.25f, whi = 0.35f;
    int b0 = 0, b1 = 0;
    unsigned int C0 = 0;

    for (;;) {
        float wscale = 1024.0f / (whi - wlo);

        for (int i = t; i < 1024; i += 256) hist[i] = 0u;
        if (t == 0) ncand = 0u;
        __syncthreads();

        unsigned int cb = 0;
        #pragma unroll
        for (int i = 0; i < 4; i++) {
            float a[4] = {vals[i].x, vals[i].y, vals[i].z, vals[i].w};
            #pragma unroll
            for (int j = 0; j < 4; j++) {
                float v = a[j];
                if (v < wlo) {
                    cb++;
                } else {
                    int bx = (int)((v - wlo) * wscale);
                    if (bx < 1024) atomicAdd(&hist[bx], 1u);
                }
            }
        }
        #pragma unroll
        for (int o = 32; o > 0; o >>= 1) cb += __shfl_xor(cb, o);
        if ((t & 63) == 0) wsum[t >> 6] = cb;
        __syncthreads();
        unsigned int Cb = wsum[0] + wsum[1] + wsum[2] + wsum[3];

        unsigned int c[4], csum = 0;
        #pragma unroll
        for (int j = 0; j < 4; j++) { c[j] = hist[t * 4 + j]; csum += c[j]; }
        unsigned int inc = csum;
        #pragma unroll
        for (int o = 1; o < 64; o <<= 1) {
            unsigned int nv = __shfl_up(inc, o);
            if ((t & 63) >= o) inc += nv;
        }
        if ((t & 63) == 63) wscan[t >> 6] = inc;
        __syncthreads();
        unsigned int wpref = 0;
        for (int wv = 0; wv < (t >> 6); wv++) wpref += wscan[wv];
        unsigned int T = wscan[0] + wscan[1] + wscan[2] + wscan[3];
        unsigned int P = Cb + wpref + inc - csum;

        unsigned int cum = P;
        #pragma unroll
        for (int j = 0; j < 4; j++) {
            unsigned int lo = cum, hi = cum + c[j];
            if (R0 >= lo && R0 < hi) { b0s = t * 4 + j; c0s = lo; }
            if (R1 >= lo && R1 < hi) { b1s = t * 4 + j; }
            cum = hi;
        }
        __syncthreads();

        if (Cb <= R0 && R1 < Cb + T) { b0 = b0s; b1 = b1s; C0 = c0s; break; }
        wlo = 0.0f; whi = 1.001f;
    }

    float wscale = 1024.0f / (whi - wlo);
    #pragma unroll
    for (int i = 0; i < 4; i++) {
        float a[4] = {vals[i].x, vals[i].y, vals[i].z, vals[i].w};
        #pragma unroll
        for (int j = 0; j < 4; j++) {
            float v = a[j];
            if (v >= wlo) {
                int bx = (int)((v - wlo) * wscale);
                if (bx >= b0 && bx <= b1) {
                    unsigned int p = atomicAdd(&ncand, 1u);
                    if (p < 256u) cand[p] = v;
                }
            }
        }
    }
    __syncthreads();
    unsigned int nc = min(ncand, 256u);
    if ((unsigned int)t < nc) {
        float v = cand[t];
        unsigned int rk = C0;
        for (unsigned int j = 0; j < nc; j++) {
            float u = cand[j];
            rk += (u < v || (u == v && j < (unsigned int)t)) ? 1u : 0u;
        }
        if (rk == R0) s0s = v;
        if (rk == R1) s1s = v;
    }
    __syncthreads();
    if (t == 0) {
        thr_out[rowid] = 0.5f * (s0s + s1s);
        min_out[rowid] = fminf(fminf(wredf[0], wredf[1]), fminf(wredf[2], wredf[3]));
    }
}

// ---------------------------------------------------------------------------
// K2: V^T via MFMA, 3-term bf16 split (Ah*Bh + Al*Bh + Ah*Bl ~ f32-accurate).
// x converted f32 -> bf16 hi/lo inline. VT[b,h,k,n] bf16 directly.
// grid = B*H*(N/64) = 512 blocks x 256 (4 waves; wave w owns n-subtile w).
// ---------------------------------------------------------------------------
__global__ __launch_bounds__(256) void value_kernel(
    const float* __restrict__ x,
    const unsigned short* __restrict__ wh, const unsigned short* __restrict__ wl,
    unsigned short* __restrict__ vt_g)
{
    int t  = threadIdx.x;
    int bid = blockIdx.x;
    int nt = bid & 63;
    int h  = (bid >> 6) & 3;
    int b  = bid >> 8;
    int n0 = nt * 64;

    int w = t >> 6, lane = t & 63, q4 = lane >> 4, m16 = lane & 15;
    int nb = n0 + w * 16;

    const float* xp = x + ((size_t)(b * Nc + nb + m16)) * HIDc + q4 * 8;

    f4v acc[4];
    #pragma unroll
    for (int kt = 0; kt < 4; kt++) acc[kt] = (f4v){0.f, 0.f, 0.f, 0.f};

    #pragma unroll
    for (int jc = 0; jc < 8; jc++) {
        float4 xv0 = *(const float4*)(xp + jc * 32);
        float4 xv1 = *(const float4*)(xp + jc * 32 + 4);
        float f[8] = {xv0.x, xv0.y, xv0.z, xv0.w, xv1.x, xv1.y, xv1.z, xv1.w};
        union { s8v v; unsigned short u[8]; } hs, ls;
        #pragma unroll
        for (int i = 0; i < 8; i++) {
            __hip_bfloat16 hb = __float2bfloat16(f[i]);
            float hf = __bfloat162float(hb);
            hs.u[i] = *(unsigned short*)&hb;
            ls.u[i] = bf16bits(f[i] - hf);
        }
        #pragma unroll
        for (int kt = 0; kt < 4; kt++) {
            size_t ao = (((size_t)(h * 4 + kt) * 8 + jc) << 9) + lane * 8;
            s8v ah = *(const s8v*)(wh + ao);
            s8v al = *(const s8v*)(wl + ao);
            acc[kt] = __builtin_amdgcn_mfma_f32_16x16x32_bf16(ah, hs.v, acc[kt], 0, 0, 0);
            acc[kt] = __builtin_amdgcn_mfma_f32_16x16x32_bf16(al, hs.v, acc[kt], 0, 0, 0);
            acc[kt] = __builtin_amdgcn_mfma_f32_16x16x32_bf16(ah, ls.v, acc[kt], 0, 0, 0);
        }
    }

    unsigned short* vg = vt_g + (((size_t)b * Hc + h) * VDc) * Nc;
    #pragma unroll
    for (int kt = 0; kt < 4; kt++) {
        #pragma unroll
        for (int rg = 0; rg < 4; rg++) {
            int k = kt * 16 + q4 * 4 + rg;
            vg[(size_t)k * Nc + nb + m16] = bf16bits(acc[kt][rg]);
        }
    }
}

// ---------------------------------------------------------------------------
// K3: fused mask + softmax-numerator + PV (bf16 MFMA), split-K over j.
// R5: T3+T4 proper — 3-stage LDS buffers (72 KB -> still 2 blocks/CU),
// depth-2 prefetch, ALL staging via global_load_lds (source-side swizzle,
// linear LDS dest), ONE raw s_barrier per iteration, COUNTED vmcnt (never 0
// in steady state; waves 0-7 stage ms+vt -> vmcnt(2), waves 8-15 vt only ->
// vmcnt(1)). Premask moved into compute: w = (d<=thm) ? exp2(...) : 0
// (identical numerics to the old BIGF premask).
// Race ledger: barrier(it) proves all waves finished compute(it-1) and their
// own STAGE(it) DMAs; STAGE(it+2) (issued after barrier(it)) overwrites only
// buf[(it-1)%3], whose last reader was compute(it-1); a runaway wave blocks
// at barrier(it+1) before it can issue STAGE(it+3) (which would touch
// buf[it%3], still being read by laggards in compute(it)).
// ---------------------------------------------------------------------------
#define NT 64
#define JT 32

__global__ __launch_bounds__(1024, 8) void attn_kernel(
    const float* __restrict__ m_dist, const float* __restrict__ rr,
    const unsigned short* __restrict__ vt_g,
    const float* __restrict__ thr_g, const float* __restrict__ min_g,
    float* __restrict__ Op, float* __restrict__ Zp, int jlen)
{
    __shared__ float msL[3][NT * JT];                  // 3 x 8 KB, f4-chunk c at c^(row&7)
    __shared__ unsigned short vtL[3][Hc * VDc * JT];   // 3 x 16 KB, 16B-chunk c at c^(row&3)

    int t = threadIdx.x;
    const int nblk = Bc * (Nc / NT);        // 128
    int js = blockIdx.x / nblk;
    int rb = blockIdx.x - js * nblk;
    int b  = rb >> 6;                       // Nc/NT = 64 row-tiles
    int n0 = (rb & 63) * NT;
    int j0 = js * jlen;

    int lane = t & 63, q = lane >> 4, m16 = lane & 15;
    int w = t >> 6;                         // wave 0..15
    int h = w & 3, rq = w >> 2;             // head, row-quad
    int row = rq * 16 + m16;                // local A-row this lane owns (0..63)

    float mn = min_g[b * Nc + n0 + row];
    float thm = thr_g[b * Nc + n0 + row];   // this lane's row threshold
    float rv = rr[h];
    float cc = -(rv * rv) * 1.4426950408889634f;   // -r^2 * log2(e)
    float nmncc = -mn * cc;                        // w = exp2(fma(d, cc, nmncc))

    f4v acc[4];
    #pragma unroll
    for (int ct = 0; ct < 4; ct++) acc[ct] = (f4v){0.f, 0.f, 0.f, 0.f};
    float zacc = 0.f;

    const float* mbase = m_dist + ((size_t)b * Nc + n0) * Nc + j0;
    const unsigned short* vtb = vt_g + ((size_t)b * Hc * VDc) * Nc + j0;

    // ms DMA staging (threads 0..511): row t>>3 (0..63), phys f4-chunk t&7,
    // logical source chunk (t&7)^(row&7). LDS dest linear = t*16 B.
    const float* msrc = mbase + (size_t)(t >> 3) * Nc + (((t & 7) ^ ((t >> 3) & 7)) << 2);
    // vt DMA staging (all threads): row t>>2 (0..255), phys 16B-chunk t&3,
    // logical source chunk (t&3)^(row&3). LDS dest linear = t*16 B.
    const unsigned short* vsrc = vtb + (size_t)(t >> 2) * Nc + (((t & 3) ^ ((t >> 2) & 3)) << 3);

    // compute-read swizzled offsets (row&7 == m16&7, vt-row&3 == m16&3)
    int s7 = m16 & 7;
    int a0o = row * JT + (((q * 2 + 0) ^ s7) << 2);
    int a1o = row * JT + (((q * 2 + 1) ^ s7) << 2);
    int bco = (q ^ (m16 & 3)) << 3;          // ushort offset within vt row
    const int hoff = h * VDc * JT;

    int niter = jlen / JT;

    #define STAGE(k, bi) do {                                                  \
        int jo_ = (k) * JT;                                                    \
        if (t < 512)                                                           \
            __builtin_amdgcn_global_load_lds(                                  \
                (const __attribute__((address_space(1))) void*)(msrc + jo_),   \
                (__attribute__((address_space(3))) void*)                      \
                    ((char*)&msL[bi][0] + (size_t)t * 16),                     \
                16, 0, 0);                                                     \
        __builtin_amdgcn_global_load_lds(                                      \
            (const __attribute__((address_space(1))) void*)(vsrc + jo_),       \
            (__attribute__((address_space(3))) void*)                          \
                ((char*)&vtL[bi][0] + (size_t)t * 16),                         \
            16, 0, 0);                                                         \
    } while (0)

    // prologue: prefetch iterations 0 and 1
    STAGE(0, 0);
    STAGE(1, 1);

    int bi = 0;
    for (int it = 0; it < niter; ++it) {
        // wait for STAGE(it); leave STAGE(it+1)'s ops in flight
        if (it + 1 < niter) {
            if (w < 8) { asm volatile("s_waitcnt vmcnt(2)" ::: "memory"); }
            else       { asm volatile("s_waitcnt vmcnt(1)" ::: "memory"); }
        } else {
            asm volatile("s_waitcnt vmcnt(0)" ::: "memory");
        }
        __builtin_amdgcn_sched_barrier(0);
        __builtin_amdgcn_s_barrier();
        __builtin_amdgcn_sched_barrier(0);

        // prefetch iteration it+2 into buf (bi+2)%3 == (it-1)%3
        if (it + 2 < niter) {
            int bn = bi + 2; if (bn >= 3) bn -= 3;
            STAGE(it + 2, bn);
        }

        // compute(it) from buf bi
        const float* msp = &msL[bi][0];
        const unsigned short* vb = &vtL[bi][hoff];
        float4 a0 = *(const float4*)(msp + a0o);
        float4 a1 = *(const float4*)(msp + a1o);
        float w0 = (a0.x <= thm) ? __builtin_amdgcn_exp2f(__builtin_fmaf(a0.x, cc, nmncc)) : 0.f;
        float w1 = (a0.y <= thm) ? __builtin_amdgcn_exp2f(__builtin_fmaf(a0.y, cc, nmncc)) : 0.f;
        float w2 = (a0.z <= thm) ? __builtin_amdgcn_exp2f(__builtin_fmaf(a0.z, cc, nmncc)) : 0.f;
        float w3 = (a0.w <= thm) ? __builtin_amdgcn_exp2f(__builtin_fmaf(a0.w, cc, nmncc)) : 0.f;
        float w4 = (a1.x <= thm) ? __builtin_amdgcn_exp2f(__builtin_fmaf(a1.x, cc, nmncc)) : 0.f;
        float w5 = (a1.y <= thm) ? __builtin_amdgcn_exp2f(__builtin_fmaf(a1.y, cc, nmncc)) : 0.f;
        float w6 = (a1.z <= thm) ? __builtin_amdgcn_exp2f(__builtin_fmaf(a1.z, cc, nmncc)) : 0.f;
        float w7 = (a1.w <= thm) ? __builtin_amdgcn_exp2f(__builtin_fmaf(a1.w, cc, nmncc)) : 0.f;
        zacc += ((w0 + w1) + (w2 + w3)) + ((w4 + w5) + (w6 + w7));
        union { s8v v; __hip_bfloat162 h2[4]; } afu;
        afu.h2[0] = __float22bfloat162_rn((float2){w0, w1});
        afu.h2[1] = __float22bfloat162_rn((float2){w2, w3});
        afu.h2[2] = __float22bfloat162_rn((float2){w4, w5});
        afu.h2[3] = __float22bfloat162_rn((float2){w6, w7});
        #pragma unroll
        for (int ct = 0; ct < 4; ct++) {
            int brow = ct * 16 + m16;
            s8v bf = *(const s8v*)(vb + brow * JT + bco);
            acc[ct] = __builtin_amdgcn_mfma_f32_16x16x32_bf16(afu.v, bf, acc[ct], 0, 0, 0);
        }
        bi = bi + 1; if (bi >= 3) bi -= 3;
    }
    #undef STAGE

    // Z: lanes sharing m16 across q (xor 16, 32)
    zacc += __shfl_xor(zacc, 16);
    zacc += __shfl_xor(zacc, 32);
    if (q == 0)
        Zp[(((size_t)js * Bc + b) * Hc + h) * Nc + n0 + row] = zacc;

    // partial O: D row = q*4+rg (within the 16), col = ct*16+m16
    #pragma unroll
    for (int ct = 0; ct < 4; ct++) {
        #pragma unroll
        for (int rg = 0; rg < 4; rg++) {
            int nl = rq * 16 + q * 4 + rg;
            Op[(((size_t)js * Bc + b) * Nc + n0 + nl) * HIDc + h * VDc + ct * 16 + m16]
                = acc[ct][rg];
        }
    }
}

// ---------------------------------------------------------------------------
// K4: combine split-K partials, normalize, exact GELU. f32x4 per thread.
// grid = B*N*HID/1024 = 2048 blocks x 256.  (unchanged)
// ---------------------------------------------------------------------------
__global__ __launch_bounds__(256) void combine_kernel(
    const float* __restrict__ Op, const float* __restrict__ Zp,
    float* __restrict__ out, int S)
{
    int g = blockIdx.x * 256 + threadIdx.x;       // float4 index
    int c4 = g & 63;
    int n  = (g >> 6) & (Nc - 1);
    int b  = g >> 18;                             // 64 * 4096 = 2^18
    int h  = c4 >> 4;

    float z = 0.f;
    float4 v = {0.f, 0.f, 0.f, 0.f};
    for (int s = 0; s < S; s++) {
        z += Zp[(((size_t)s * Bc + b) * Hc + h) * Nc + n];
        float4 p = *(const float4*)&Op[(((size_t)s * Bc + b) * Nc + n) * HIDc + c4 * 4];
        v.x += p.x; v.y += p.y; v.z += p.z; v.w += p.w;
    }
    float iz = 1.0f / z;
    float4 o;
    float u;
    u = v.x * iz; o.x = 0.5f * u * (1.0f + erff(u * 0.7071067811865476f));
    u = v.y * iz; o.y = 0.5f * u * (1.0f + erff(u * 0.7071067811865476f));
    u = v.z * iz; o.z = 0.5f * u * (1.0f + erff(u * 0.7071067811865476f));
    u = v.w * iz; o.w = 0.5f * u * (1.0f + erff(u * 0.7071067811865476f));
    *(float4*)&out[(((size_t)b * Nc + n) * HIDc) + c4 * 4] = o;
}

// ---------------------------------------------------------------------------
extern "C" void kernel_launch(void* const* d_in, const int* in_sizes, int n_in,
                              void* d_out, int out_size, void* d_ws, size_t ws_size,
                              hipStream_t stream) {
    const float* m_dist = (const float*)d_in[0];
    const float* x      = (const float*)d_in[1];
    const float* r      = (const float*)d_in[2];
    const float* weight = (const float*)d_in[3];
    float* out = (float*)d_out;

    char* ws = (char*)d_ws;
    const size_t MB = 1024 * 1024;
    unsigned short* vt = (unsigned short*)ws;            // 4 MiB bf16 VT
    float* thr = (float*)(ws + 4 * MB);                  // 32 KiB
    float* mn  = (float*)(ws + 4 * MB + 32 * 1024);      // 32 KiB
    float* Zp  = (float*)(ws + 4 * MB + 64 * 1024);      // up to 512 KiB
    float* Op  = (float*)(ws + 5 * MB);                  // S * 8 MiB

    const size_t OpSz = (size_t)Bc * Nc * HIDc * 4;      // 8 MiB
    // split factor: prefer 4, else 2, else 1 (needs 5MB + S*OpSz + 256KB)
    int S = 4;
    if (ws_size < 6 * MB + 4 * OpSz) S = 2;
    if (ws_size < 6 * MB + 2 * OpSz) S = 1;
    int jlen = Nc / S;

    // W hi/lo fragment buffers after Op (128 KiB each)
    char* pb = ws + 5 * MB + (size_t)S * OpSz;
    unsigned short* wh = (unsigned short*)pb;
    unsigned short* wl = (unsigned short*)(pb + 128 * 1024);

    front_kernel<<<128 + Bc * Nc, 256, 0, stream>>>(m_dist, weight, wh, wl, thr, mn);
    value_kernel<<<512, 256, 0, stream>>>(x, wh, wl, vt);
    attn_kernel<<<S * Bc * (Nc / NT), 1024, 0, stream>>>(m_dist, r, vt, thr, mn, Op, Zp, jlen);
    combine_kernel<<<(Bc * Nc * HIDc) / 1024, 256, 0, stream>>>(Op, Zp, out, S);
}